// Round 15
// baseline (204.536 us; speedup 1.0000x reference)
//
#include <hip/hip_runtime.h>
#include <hip/hip_cooperative_groups.h>

namespace cg = cooperative_groups;

#define NA 100000
#define NE 300000
#define STEPS 4
#define NTILES (NE / 16)        // 18750 (exact)
#define ATILES (NA / 16)        // 6250  (exact)
#define GBLK 512                // cooperative grid: 2 blocks/CU x 256 CUs

typedef _Float16 f16;
typedef _Float16 half8 __attribute__((ext_vector_type(8)));
using f32x4 = __attribute__((ext_vector_type(4))) float;

__device__ __forceinline__ float f16lo(unsigned int v) {
    return (float)__builtin_bit_cast(f16, (unsigned short)(v & 0xffffu));
}
__device__ __forceinline__ float f16hi(unsigned int v) {
    return (float)__builtin_bit_cast(f16, (unsigned short)(v >> 16));
}

// ---------------------------------------------------------------------------
// setup: h fp32->fp16, zero rowcnt + total, preconvert all weights to fp16.
// ---------------------------------------------------------------------------
__global__ __launch_bounds__(256) void setup_kernel(
    const float* __restrict__ atom,
    const float* __restrict__ Wb, const float* __restrict__ bb,
    const float* __restrict__ Wih, const float* __restrict__ Whh,
    f16* __restrict__ hbf, f16* __restrict__ Wbt,
    f16* __restrict__ Wihb, f16* __restrict__ Whhb,
    int* __restrict__ rowcnt, int* __restrict__ total)
{
    int t = blockIdx.x * 256 + threadIdx.x;
    const int NH8 = NA * 32 / 8;                 // 400000
    if (t < NH8) {
        float4 a = reinterpret_cast<const float4*>(atom)[2 * t];
        float4 b = reinterpret_cast<const float4*>(atom)[2 * t + 1];
        half8 o;
        o[0]=(f16)a.x; o[1]=(f16)a.y; o[2]=(f16)a.z; o[3]=(f16)a.w;
        o[4]=(f16)b.x; o[5]=(f16)b.y; o[6]=(f16)b.z; o[7]=(f16)b.w;
        reinterpret_cast<half8*>(hbf)[t] = o;
        return;
    }
    int u = t - NH8;
    if (u < NA) {
        rowcnt[u] = 0;
        if (u == 0) *total = 0;
        return;
    }
    int v = u - NA;
    if (v < 17 * 32 * 32) {
        int j = v & 31, i = (v >> 5) & 31, k = v >> 10;
        float val = (k < 16) ? Wb[k * 1024 + i * 32 + j] : bb[i * 32 + j];
        int row = ((i & 4) ? 16 : 0) + ((i >> 3) << 2) + (i & 3);  // i = kg*8.. permute
        Wbt[(k * 32 + row) * 32 + j] = (f16)val;
    } else if (v < 17 * 32 * 32 + 3072) {
        int q = v - 17 * 32 * 32;
        Wihb[q] = (f16)Wih[q];
    } else if (v < 17 * 32 * 32 + 6144) {
        int q = v - 17 * 32 * 32 - 3072;
        Whhb[q] = (f16)Whh[q];
    }
}

__global__ __launch_bounds__(256) void hist_kernel(
    const int* __restrict__ pair, int* __restrict__ cnt)
{
    int e = blockIdx.x * 256 + threadIdx.x;
    if (e < NE) atomicAdd(&cnt[reinterpret_cast<const int2*>(pair)[e].x], 1);
}

// one-kernel segment allocation: block-local prefix + atomic base.
__global__ __launch_bounds__(1024) void alloc_kernel(
    const int* __restrict__ cnt, int* __restrict__ start,
    int* __restrict__ next, int* __restrict__ total)
{
    __shared__ int tmp[1024];
    __shared__ int base;
    int g = blockIdx.x * 1024 + threadIdx.x;
    int v = (g < NA) ? cnt[g] : 0;
    tmp[threadIdx.x] = v;
    __syncthreads();
    for (int off = 1; off < 1024; off <<= 1) {
        int u = (threadIdx.x >= off) ? tmp[threadIdx.x - off] : 0;
        __syncthreads();
        tmp[threadIdx.x] += u;
        __syncthreads();
    }
    if (threadIdx.x == 1023) base = atomicAdd(total, tmp[1023]);
    __syncthreads();
    if (g < NA) {
        int s = base + tmp[threadIdx.x] - v;
        start[g] = s;
        next[g] = s;
    }
}

__global__ __launch_bounds__(256) void scatter_kernel(
    const float* __restrict__ bond, const int* __restrict__ pair,
    int* __restrict__ next, int* __restrict__ nbrp, f16* __restrict__ bondp)
{
    int e = blockIdx.x * 256 + threadIdx.x;
    if (e >= NE) return;
    int2 p = reinterpret_cast<const int2*>(pair)[e];
    int pos = atomicAdd(&next[p.x], 1);
    nbrp[pos] = p.y;
    const float4* b4 = reinterpret_cast<const float4*>(bond + (size_t)e * 16);
    float4 b0 = b4[0], b1 = b4[1], b2 = b4[2], b3 = b4[3];
    half8 o0, o1;
    o0[0]=(f16)b0.x; o0[1]=(f16)b0.y; o0[2]=(f16)b0.z; o0[3]=(f16)b0.w;
    o0[4]=(f16)b1.x; o0[5]=(f16)b1.y; o0[6]=(f16)b1.z; o0[7]=(f16)b1.w;
    o1[0]=(f16)b2.x; o1[1]=(f16)b2.y; o1[2]=(f16)b2.z; o1[3]=(f16)b2.w;
    o1[4]=(f16)b3.x; o1[5]=(f16)b3.y; o1[6]=(f16)b3.z; o1[7]=(f16)b3.w;
    half8* dst = reinterpret_cast<half8*>(bondp + (size_t)pos * 16);
    dst[0] = o0; dst[1] = o1;
}

// ---------------------------------------------------------------------------
// r12-proven phase bodies (fallback path)
// ---------------------------------------------------------------------------
__device__ __forceinline__ void msg_body(
    const f16* __restrict__ h, const f16* __restrict__ bondp,
    const int* __restrict__ nbrp, const f16* __restrict__ Wbt,
    f16* __restrict__ msgb, int wid, int nw, int col, int kg)
{
    half8 w0[17], w1[17];
#pragma unroll
    for (int t = 0; t < 17; ++t) {
        w0[t] = *reinterpret_cast<const half8*>(Wbt + (t * 32 + col) * 32 + kg * 8);
        w1[t] = *reinterpret_cast<const half8*>(Wbt + (t * 32 + 16 + col) * 32 + kg * 8);
    }
    int tile = wid;
    int pos = 0;
    half8 hf{}, cA{}, cB{};
    if (tile < NTILES) {
        pos = tile * 16 + col;
        int nbr0 = nbrp[pos];
        cA = *reinterpret_cast<const half8*>(bondp + (size_t)pos * 16);
        cB = *reinterpret_cast<const half8*>(bondp + (size_t)pos * 16 + 8);
        hf = *reinterpret_cast<const half8*>(h + (size_t)nbr0 * 32 + kg * 8);
    }
    while (tile < NTILES) {
        int tile2 = tile + nw;
        int pos2 = 0;
        half8 hf2{}, cA2{}, cB2{};
        if (tile2 < NTILES) {
            pos2 = tile2 * 16 + col;
            int nbr2 = nbrp[pos2];
            cA2 = *reinterpret_cast<const half8*>(bondp + (size_t)pos2 * 16);
            cB2 = *reinterpret_cast<const half8*>(bondp + (size_t)pos2 * 16 + 8);
            hf2 = *reinterpret_cast<const half8*>(h + (size_t)nbr2 * 32 + kg * 8);
        }
        f32x4 acc0 = {0.f, 0.f, 0.f, 0.f};
        f32x4 acc1 = {0.f, 0.f, 0.f, 0.f};
#pragma unroll
        for (int t = 0; t < 16; ++t) {
            f16 ch = (t < 8) ? cA[t] : cB[t - 8];
            half8 a = hf * ch;
            acc0 = __builtin_amdgcn_mfma_f32_16x16x32_f16(w0[t], a, acc0, 0, 0, 0);
            acc1 = __builtin_amdgcn_mfma_f32_16x16x32_f16(w1[t], a, acc1, 0, 0, 0);
        }
        acc0 = __builtin_amdgcn_mfma_f32_16x16x32_f16(w0[16], hf, acc0, 0, 0, 0);
        acc1 = __builtin_amdgcn_mfma_f32_16x16x32_f16(w1[16], hf, acc1, 0, 0, 0);

        half8 so;
        so[0]=(f16)acc0[0]; so[1]=(f16)acc0[1]; so[2]=(f16)acc0[2]; so[3]=(f16)acc0[3];
        so[4]=(f16)acc1[0]; so[5]=(f16)acc1[1]; so[6]=(f16)acc1[2]; so[7]=(f16)acc1[3];
        *reinterpret_cast<half8*>(msgb + (size_t)pos * 32 + kg * 8) = so;

        tile = tile2; pos = pos2; hf = hf2; cA = cA2; cB = cB2;
    }
}

__device__ __forceinline__ void gru_body(
    const f16* __restrict__ msgb, const int* __restrict__ start,
    const int* __restrict__ cnt, f16* __restrict__ h,
    const f16* __restrict__ Wihb, const f16* __restrict__ Whhb,
    const float* __restrict__ bih, const float* __restrict__ bhh,
    float* __restrict__ hout, int wf, int wid, int nw, int col, int kg)
{
    half8 wi[6], wh[6];
#pragma unroll
    for (int t = 0; t < 6; ++t) {
        wi[t] = *reinterpret_cast<const half8*>(Wihb + (size_t)(t * 16 + col) * 32 + kg * 8);
        wh[t] = *reinterpret_cast<const half8*>(Whhb + (size_t)(t * 16 + col) * 32 + kg * 8);
    }
    float br0  = bih[col]      + bhh[col];
    float bz0  = bih[32 + col] + bhh[32 + col];
    float bin0 = bih[64 + col];
    float bhn0 = bhh[64 + col];
    float br1  = bih[16 + col] + bhh[16 + col];
    float bz1  = bih[48 + col] + bhh[48 + col];
    float bin1 = bih[80 + col];
    float bhn1 = bhh[80 + col];

    for (int tile = wid; tile < ATILES; tile += nw) {
        int base = tile * 16;
        int a0   = base + col;
        int st = start[a0], en = st + cnt[a0];
        half8 hfrag = *reinterpret_cast<const half8*>(h + (size_t)a0 * 32 + kg * 8);

        float xs[8] = {0.f, 0.f, 0.f, 0.f, 0.f, 0.f, 0.f, 0.f};
        for (int p = st; p < en; ++p) {
            half8 m = *reinterpret_cast<const half8*>(msgb + (size_t)p * 32 + kg * 8);
#pragma unroll
            for (int j = 0; j < 8; ++j) xs[j] += (float)m[j];
        }
        half8 xfrag;
#pragma unroll
        for (int j = 0; j < 8; ++j) xfrag[j] = (f16)xs[j];

        f32x4 gi[6], gh[6];
#pragma unroll
        for (int t = 0; t < 6; ++t) {
            f32x4 z = {0.f, 0.f, 0.f, 0.f};
            gi[t] = __builtin_amdgcn_mfma_f32_16x16x32_f16(xfrag, wi[t], z, 0, 0, 0);
            gh[t] = __builtin_amdgcn_mfma_f32_16x16x32_f16(hfrag, wh[t], z, 0, 0, 0);
        }
#pragma unroll
        for (int hh = 0; hh < 2; ++hh) {
            float br  = hh ? br1  : br0;
            float bz  = hh ? bz1  : bz0;
            float bin = hh ? bin1 : bin0;
            float bhn = hh ? bhn1 : bhn0;
            int i = hh * 16 + col;
#pragma unroll
            for (int reg = 0; reg < 4; ++reg) {
                int a = base + kg * 4 + reg;
                float r = 1.f / (1.f + __expf(-(gi[hh][reg] + gh[hh][reg] + br)));
                float z = 1.f / (1.f + __expf(-(gi[2 + hh][reg] + gh[2 + hh][reg] + bz)));
                float n = tanhf(gi[4 + hh][reg] + bin + r * (gh[4 + hh][reg] + bhn));
                float hp = (float)h[(size_t)a * 32 + i];
                float o  = (1.f - z) * n + z * hp;
                if (wf) hout[(size_t)a * 32 + i] = o;
                h[(size_t)a * 32 + i] = (f16)o;
            }
        }
    }
}

__global__ __launch_bounds__(256, 2) void msg_kernel(
    const f16* __restrict__ hb, const f16* __restrict__ bondp,
    const int* __restrict__ nbrp, const f16* __restrict__ Wbt,
    f16* __restrict__ msgb)
{
    int wave = threadIdx.x >> 6;
    int lane = threadIdx.x & 63;
    msg_body(hb, bondp, nbrp, Wbt, msgb,
             blockIdx.x * 4 + wave, gridDim.x << 2, lane & 15, lane >> 4);
}

__global__ __launch_bounds__(256) void gru_kernel(
    const f16* __restrict__ msgb, const int* __restrict__ start,
    const int* __restrict__ cnt, f16* __restrict__ hb,
    const f16* __restrict__ Wihb, const f16* __restrict__ Whhb,
    const float* __restrict__ bih, const float* __restrict__ bhh,
    float* __restrict__ hout, int wf)
{
    int wave = threadIdx.x >> 6;
    int lane = threadIdx.x & 63;
    gru_body(msgb, start, cnt, hb, Wihb, Whhb, bih, bhh, hout, wf,
             blockIdx.x * 4 + wave, gridDim.x << 2, lane & 15, lane >> 4);
}

// ---------------------------------------------------------------------------
// Fused msg+gru per atom-tile: one wave owns 16 atoms; per 16-edge chunk run
// the msg MFMAs, shfl-segment-reduce into the GRU x-accumulator (no msgb,
// no LDS scratch, no barrier — wave-synchronous). GRU weights in LDS.
// h double-buffered -> ONE grid.sync per step.
// ---------------------------------------------------------------------------
__global__ __launch_bounds__(256, 2) void fused_kernel(
    f16* __restrict__ h0buf, f16* __restrict__ h1buf,
    const f16* __restrict__ bondp, const int* __restrict__ nbrp,
    const f16* __restrict__ Wbt, const int* __restrict__ start,
    const int* __restrict__ cnt,
    const f16* __restrict__ Wihb, const f16* __restrict__ Whhb,
    const float* __restrict__ bih, const float* __restrict__ bhh,
    float* __restrict__ hout)
{
    __shared__ f16 lwi[96 * 32];
    __shared__ f16 lwh[96 * 32];
    for (int t = threadIdx.x; t < 96 * 32 / 8; t += 256) {
        reinterpret_cast<half8*>(lwi)[t] = reinterpret_cast<const half8*>(Wihb)[t];
        reinterpret_cast<half8*>(lwh)[t] = reinterpret_cast<const half8*>(Whhb)[t];
    }
    __syncthreads();

    cg::grid_group grid = cg::this_grid();
    int wave = threadIdx.x >> 6;
    int lane = threadIdx.x & 63;
    int col  = lane & 15;
    int kg   = lane >> 4;
    int wid  = blockIdx.x * 4 + wave;
    int nw   = gridDim.x << 2;

    // msg weights register-resident for the whole kernel
    half8 w0[17], w1[17];
#pragma unroll
    for (int t = 0; t < 17; ++t) {
        w0[t] = *reinterpret_cast<const half8*>(Wbt + (t * 32 + col) * 32 + kg * 8);
        w1[t] = *reinterpret_cast<const half8*>(Wbt + (t * 32 + 16 + col) * 32 + kg * 8);
    }
    float br0  = bih[col]      + bhh[col];
    float bz0  = bih[32 + col] + bhh[32 + col];
    float bin0 = bih[64 + col];
    float bhn0 = bhh[64 + col];
    float br1  = bih[16 + col] + bhh[16 + col];
    float bz1  = bih[48 + col] + bhh[48 + col];
    float bin1 = bih[80 + col];
    float bhn1 = bhh[80 + col];

    f16* hp = h0buf;       // read buffer (h_prev)
    f16* hn = h1buf;       // write buffer (h_next)

    for (int s = 0; s < STEPS; ++s) {
        int wf = (s == STEPS - 1);
        for (int tile = wid; tile < ATILES; tile += nw) {
            int base = tile * 16;
            int a0   = base + col;
            int st = start[a0], en = st + cnt[a0];
            // tile's contiguous edge range (tiles never cross alloc blocks)
            int tb = __shfl(st, lane & 48);           // col==0 lane's st
            int te = __shfl(en, (lane & 48) | 15);    // col==15 lane's en

            float xs[8] = {0.f, 0.f, 0.f, 0.f, 0.f, 0.f, 0.f, 0.f};

            for (int cb = tb; cb < te; cb += 16) {
                int el = cb + col;
                int elc = (el < te) ? el : (te - 1);          // clamp (safe loads)
                int nbr = nbrp[elc];
                half8 cA = *reinterpret_cast<const half8*>(bondp + (size_t)elc * 16);
                half8 cB = *reinterpret_cast<const half8*>(bondp + (size_t)elc * 16 + 8);
                half8 hf = *reinterpret_cast<const half8*>(hp + (size_t)nbr * 32 + kg * 8);

                f32x4 acc0 = {0.f, 0.f, 0.f, 0.f};
                f32x4 acc1 = {0.f, 0.f, 0.f, 0.f};
#pragma unroll
                for (int t = 0; t < 16; ++t) {
                    f16 ch = (t < 8) ? cA[t] : cB[t - 8];
                    half8 a = hf * ch;
                    acc0 = __builtin_amdgcn_mfma_f32_16x16x32_f16(w0[t], a, acc0, 0, 0, 0);
                    acc1 = __builtin_amdgcn_mfma_f32_16x16x32_f16(w1[t], a, acc1, 0, 0, 0);
                }
                acc0 = __builtin_amdgcn_mfma_f32_16x16x32_f16(w0[16], hf, acc0, 0, 0, 0);
                acc1 = __builtin_amdgcn_mfma_f32_16x16x32_f16(w1[16], hf, acc1, 0, 0, 0);

                // pack to f16 (same rounding as msgb path) -> 4 dwords
                union { half8 hh8; unsigned int u[4]; } pk;
                pk.hh8[0]=(f16)acc0[0]; pk.hh8[1]=(f16)acc0[1];
                pk.hh8[2]=(f16)acc0[2]; pk.hh8[3]=(f16)acc0[3];
                pk.hh8[4]=(f16)acc1[0]; pk.hh8[5]=(f16)acc1[1];
                pk.hh8[6]=(f16)acc1[2]; pk.hh8[7]=(f16)acc1[3];

                // segment-reduce: lane (col,kg) pulls rows of atom a0 from
                // lanes (r,kg). Position-ascending order == r12 order.
                int lo = st > cb ? st : cb;
                int hi = en < cb + 16 ? en : cb + 16;
                int mylen = hi - lo; if (mylen < 0) mylen = 0;
                int rbase = lo - cb;
                for (int it = 0; it < 16; ++it) {
                    if (__all(it >= mylen)) break;
                    int srcl = (lane & 48) | ((rbase + it) & 15);
                    unsigned int v0 = __shfl(pk.u[0], srcl);
                    unsigned int v1 = __shfl(pk.u[1], srcl);
                    unsigned int v2 = __shfl(pk.u[2], srcl);
                    unsigned int v3 = __shfl(pk.u[3], srcl);
                    if (it < mylen) {
                        xs[0] += f16lo(v0); xs[1] += f16hi(v0);
                        xs[2] += f16lo(v1); xs[3] += f16hi(v1);
                        xs[4] += f16lo(v2); xs[5] += f16hi(v2);
                        xs[6] += f16lo(v3); xs[7] += f16hi(v3);
                    }
                }
            }

            // ---- GRU for this tile (weights from LDS) ----
            half8 xfrag;
#pragma unroll
            for (int j = 0; j < 8; ++j) xfrag[j] = (f16)xs[j];
            half8 hfrag = *reinterpret_cast<const half8*>(hp + (size_t)a0 * 32 + kg * 8);

            f32x4 gi[6], gh[6];
#pragma unroll
            for (int t = 0; t < 6; ++t) {
                half8 wiF = *reinterpret_cast<const half8*>(lwi + (t * 16 + col) * 32 + kg * 8);
                half8 whF = *reinterpret_cast<const half8*>(lwh + (t * 16 + col) * 32 + kg * 8);
                f32x4 z = {0.f, 0.f, 0.f, 0.f};
                gi[t] = __builtin_amdgcn_mfma_f32_16x16x32_f16(xfrag, wiF, z, 0, 0, 0);
                gh[t] = __builtin_amdgcn_mfma_f32_16x16x32_f16(hfrag, whF, z, 0, 0, 0);
            }
#pragma unroll
            for (int hh = 0; hh < 2; ++hh) {
                float br  = hh ? br1  : br0;
                float bz  = hh ? bz1  : bz0;
                float bin = hh ? bin1 : bin0;
                float bhn = hh ? bhn1 : bhn0;
                int i = hh * 16 + col;
#pragma unroll
                for (int reg = 0; reg < 4; ++reg) {
                    int a = base + kg * 4 + reg;
                    float r = 1.f / (1.f + __expf(-(gi[hh][reg] + gh[hh][reg] + br)));
                    float z = 1.f / (1.f + __expf(-(gi[2 + hh][reg] + gh[2 + hh][reg] + bz)));
                    float n = tanhf(gi[4 + hh][reg] + bin + r * (gh[4 + hh][reg] + bhn));
                    float hpv = (float)hp[(size_t)a * 32 + i];
                    float o   = (1.f - z) * n + z * hpv;
                    if (wf) hout[(size_t)a * 32 + i] = o;
                    hn[(size_t)a * 32 + i] = (f16)o;
                }
            }
        }
        grid.sync();
        f16* tmp = hp; hp = hn; hn = tmp;
    }
}

extern "C" void kernel_launch(void* const* d_in, const int* in_sizes, int n_in,
                              void* d_out, int out_size, void* d_ws, size_t ws_size,
                              hipStream_t stream)
{
    const float* atom = (const float*)d_in[0];
    const float* bond = (const float*)d_in[1];
    const int*   pair = (const int*)  d_in[2];
    const float* Wb   = (const float*)d_in[3];
    const float* bb   = (const float*)d_in[4];
    const float* W_ih = (const float*)d_in[5];
    const float* W_hh = (const float*)d_in[6];
    const float* b_ih = (const float*)d_in[7];
    const float* b_hh = (const float*)d_in[8];
    float* out = (float*)d_out;

    char* w = (char*)d_ws;
    f16* msg    = (f16*)w;                       // 19,200,000 B (fallback only)
    f16* h1     = (f16*)w;                       //  6,400,000   (fused: aliases msg)
    f16* hbf    = (f16*)(w + 19200000);          //  6,400,000
    f16* bondp  = (f16*)(w + 25600000);          //  9,600,000
    f16* Wbt    = (f16*)(w + 35200000);          //     34,816
    f16* Wihb   = Wbt + 17 * 32 * 32;            //      6,144
    f16* Whhb   = Wihb + 96 * 32;                //      6,144
    int* rowcnt = (int*)(w + 35248000);          //    400,000
    int* startp = (int*)(w + 35648000);          //    400,000
    int* nextp  = (int*)(w + 36048000);          //    400,000
    int* nbrp   = (int*)(w + 36448000);          //  1,200,000
    int* total  = (int*)(w + 37648000);          //          4

    // --- setup + CSR build (4 launches) ---
    const int setup_threads = NA * 32 / 8 + NA + 17 * 32 * 32 + 6144;
    setup_kernel<<<(setup_threads + 255) / 256, 256, 0, stream>>>(
        atom, Wb, bb, W_ih, W_hh, hbf, Wbt, Wihb, Whhb, rowcnt, total);
    hist_kernel<<<(NE + 255) / 256, 256, 0, stream>>>(pair, rowcnt);
    alloc_kernel<<<(NA + 1023) / 1024, 1024, 0, stream>>>(rowcnt, startp, nextp, total);
    scatter_kernel<<<(NE + 255) / 256, 256, 0, stream>>>(bond, pair, nextp, nbrp, bondp);

    // --- step loop: fused cooperative if co-residency-safe ---
    int bpc = 0;
    hipError_t qe = hipOccupancyMaxActiveBlocksPerMultiprocessor(
        &bpc, (const void*)fused_kernel, 256, 0);
    if (qe == hipSuccess && bpc >= 2) {
        void* args[12];
        args[0]  = &hbf;    args[1]  = &h1;     args[2]  = &bondp;
        args[3]  = &nbrp;   args[4]  = &Wbt;    args[5]  = &startp;
        args[6]  = &rowcnt; args[7]  = &Wihb;   args[8]  = &Whhb;
        args[9]  = (void*)&b_ih; args[10] = (void*)&b_hh; args[11] = &out;
        hipLaunchCooperativeKernel((void*)fused_kernel, dim3(GBLK), dim3(256),
                                   args, 0, stream);
    } else {
        const int gru_blocks = (ATILES + 3) / 4;
        for (int s = 0; s < STEPS; ++s) {
            msg_kernel<<<512, 256, 0, stream>>>(hbf, bondp, nbrp, Wbt, msg);
            gru_kernel<<<gru_blocks, 256, 0, stream>>>(msg, startp, rowcnt, hbf,
                                                       Wihb, Whhb, b_ih, b_hh, out,
                                                       (s == STEPS - 1) ? 1 : 0);
        }
    }
}

// Round 16
// 195.125 us; speedup vs baseline: 1.0482x; 1.0482x over previous
//
#include <hip/hip_runtime.h>
#include <hip/hip_cooperative_groups.h>

namespace cg = cooperative_groups;

#define NA 100000
#define NE 300000
#define STEPS 4
#define NTILES (NE / 16)        // 18750 (exact)
#define ATILES (NA / 16)        // 6250  (exact)

typedef _Float16 f16;
typedef _Float16 half8 __attribute__((ext_vector_type(8)));
using f32x4 = __attribute__((ext_vector_type(4))) float;

// ---------------------------------------------------------------------------
// setup: h fp32->fp16, zero rowcnt + total, preconvert all weights to fp16.
// ---------------------------------------------------------------------------
__global__ __launch_bounds__(256) void setup_kernel(
    const float* __restrict__ atom,
    const float* __restrict__ Wb, const float* __restrict__ bb,
    const float* __restrict__ Wih, const float* __restrict__ Whh,
    f16* __restrict__ hbf, f16* __restrict__ Wbt,
    f16* __restrict__ Wihb, f16* __restrict__ Whhb,
    int* __restrict__ rowcnt, int* __restrict__ total)
{
    int t = blockIdx.x * 256 + threadIdx.x;
    const int NH8 = NA * 32 / 8;                 // 400000
    if (t < NH8) {
        float4 a = reinterpret_cast<const float4*>(atom)[2 * t];
        float4 b = reinterpret_cast<const float4*>(atom)[2 * t + 1];
        half8 o;
        o[0]=(f16)a.x; o[1]=(f16)a.y; o[2]=(f16)a.z; o[3]=(f16)a.w;
        o[4]=(f16)b.x; o[5]=(f16)b.y; o[6]=(f16)b.z; o[7]=(f16)b.w;
        reinterpret_cast<half8*>(hbf)[t] = o;
        return;
    }
    int u = t - NH8;
    if (u < NA) {
        rowcnt[u] = 0;
        if (u == 0) *total = 0;
        return;
    }
    int v = u - NA;
    if (v < 17 * 32 * 32) {
        int j = v & 31, i = (v >> 5) & 31, k = v >> 10;
        float val = (k < 16) ? Wb[k * 1024 + i * 32 + j] : bb[i * 32 + j];
        int row = ((i & 4) ? 16 : 0) + ((i >> 3) << 2) + (i & 3);  // i = kg*8.. permute
        Wbt[(k * 32 + row) * 32 + j] = (f16)val;
    } else if (v < 17 * 32 * 32 + 3072) {
        int q = v - 17 * 32 * 32;
        Wihb[q] = (f16)Wih[q];
    } else if (v < 17 * 32 * 32 + 6144) {
        int q = v - 17 * 32 * 32 - 3072;
        Whhb[q] = (f16)Whh[q];
    }
}

__global__ __launch_bounds__(256) void hist_kernel(
    const int* __restrict__ pair, int* __restrict__ cnt)
{
    int e = blockIdx.x * 256 + threadIdx.x;
    if (e < NE) atomicAdd(&cnt[reinterpret_cast<const int2*>(pair)[e].x], 1);
}

// one-kernel segment allocation: block-local prefix + atomic base.
__global__ __launch_bounds__(1024) void alloc_kernel(
    const int* __restrict__ cnt, int* __restrict__ start,
    int* __restrict__ next, int* __restrict__ total)
{
    __shared__ int tmp[1024];
    __shared__ int base;
    int g = blockIdx.x * 1024 + threadIdx.x;
    int v = (g < NA) ? cnt[g] : 0;
    tmp[threadIdx.x] = v;
    __syncthreads();
    for (int off = 1; off < 1024; off <<= 1) {
        int u = (threadIdx.x >= off) ? tmp[threadIdx.x - off] : 0;
        __syncthreads();
        tmp[threadIdx.x] += u;
        __syncthreads();
    }
    if (threadIdx.x == 1023) base = atomicAdd(total, tmp[1023]);
    __syncthreads();
    if (g < NA) {
        int s = base + tmp[threadIdx.x] - v;
        start[g] = s;
        next[g] = s;
    }
}

__global__ __launch_bounds__(256) void scatter_kernel(
    const float* __restrict__ bond, const int* __restrict__ pair,
    int* __restrict__ next, int* __restrict__ nbrp, f16* __restrict__ bondp)
{
    int e = blockIdx.x * 256 + threadIdx.x;
    if (e >= NE) return;
    int2 p = reinterpret_cast<const int2*>(pair)[e];
    int pos = atomicAdd(&next[p.x], 1);
    nbrp[pos] = p.y;
    const float4* b4 = reinterpret_cast<const float4*>(bond + (size_t)e * 16);
    float4 b0 = b4[0], b1 = b4[1], b2 = b4[2], b3 = b4[3];
    half8 o0, o1;
    o0[0]=(f16)b0.x; o0[1]=(f16)b0.y; o0[2]=(f16)b0.z; o0[3]=(f16)b0.w;
    o0[4]=(f16)b1.x; o0[5]=(f16)b1.y; o0[6]=(f16)b1.z; o0[7]=(f16)b1.w;
    o1[0]=(f16)b2.x; o1[1]=(f16)b2.y; o1[2]=(f16)b2.z; o1[3]=(f16)b2.w;
    o1[4]=(f16)b3.x; o1[5]=(f16)b3.y; o1[6]=(f16)b3.z; o1[7]=(f16)b3.w;
    half8* dst = reinterpret_cast<half8*>(bondp + (size_t)pos * 16);
    dst[0] = o0; dst[1] = o1;
}

// ---------------------------------------------------------------------------
// shared phase bodies (identical arithmetic to proven r11/r12/r14 kernels)
// ---------------------------------------------------------------------------
__device__ __forceinline__ void msg_body(
    const f16* __restrict__ h, const f16* __restrict__ bondp,
    const int* __restrict__ nbrp, const f16* __restrict__ Wbt,
    f16* __restrict__ msgb, int wid, int nw, int col, int kg)
{
    half8 w0[17], w1[17];
#pragma unroll
    for (int t = 0; t < 17; ++t) {
        w0[t] = *reinterpret_cast<const half8*>(Wbt + (t * 32 + col) * 32 + kg * 8);
        w1[t] = *reinterpret_cast<const half8*>(Wbt + (t * 32 + 16 + col) * 32 + kg * 8);
    }
    int tile = wid;
    int pos = 0;
    half8 hf{}, cA{}, cB{};
    if (tile < NTILES) {
        pos = tile * 16 + col;
        int nbr0 = nbrp[pos];
        cA = *reinterpret_cast<const half8*>(bondp + (size_t)pos * 16);
        cB = *reinterpret_cast<const half8*>(bondp + (size_t)pos * 16 + 8);
        hf = *reinterpret_cast<const half8*>(h + (size_t)nbr0 * 32 + kg * 8);
    }
    while (tile < NTILES) {
        int tile2 = tile + nw;
        int pos2 = 0;
        half8 hf2{}, cA2{}, cB2{};
        if (tile2 < NTILES) {
            pos2 = tile2 * 16 + col;
            int nbr2 = nbrp[pos2];
            cA2 = *reinterpret_cast<const half8*>(bondp + (size_t)pos2 * 16);
            cB2 = *reinterpret_cast<const half8*>(bondp + (size_t)pos2 * 16 + 8);
            hf2 = *reinterpret_cast<const half8*>(h + (size_t)nbr2 * 32 + kg * 8);
        }
        f32x4 acc0 = {0.f, 0.f, 0.f, 0.f};
        f32x4 acc1 = {0.f, 0.f, 0.f, 0.f};
#pragma unroll
        for (int t = 0; t < 16; ++t) {
            f16 ch = (t < 8) ? cA[t] : cB[t - 8];
            half8 a = hf * ch;               // v_pk_mul_f16 x4
            acc0 = __builtin_amdgcn_mfma_f32_16x16x32_f16(w0[t], a, acc0, 0, 0, 0);
            acc1 = __builtin_amdgcn_mfma_f32_16x16x32_f16(w1[t], a, acc1, 0, 0, 0);
        }
        acc0 = __builtin_amdgcn_mfma_f32_16x16x32_f16(w0[16], hf, acc0, 0, 0, 0);
        acc1 = __builtin_amdgcn_mfma_f32_16x16x32_f16(w1[16], hf, acc1, 0, 0, 0);

        half8 so;   // i = kg*8 .. kg*8+7 (contiguous via Wbt row permute)
        so[0]=(f16)acc0[0]; so[1]=(f16)acc0[1]; so[2]=(f16)acc0[2]; so[3]=(f16)acc0[3];
        so[4]=(f16)acc1[0]; so[5]=(f16)acc1[1]; so[6]=(f16)acc1[2]; so[7]=(f16)acc1[3];
        *reinterpret_cast<half8*>(msgb + (size_t)pos * 32 + kg * 8) = so;

        tile = tile2; pos = pos2; hf = hf2; cA = cA2; cB = cB2;
    }
}

__device__ __forceinline__ void gru_body(
    const f16* __restrict__ msgb, const int* __restrict__ start,
    const int* __restrict__ cnt, f16* __restrict__ h,
    const f16* __restrict__ Wihb, const f16* __restrict__ Whhb,
    const float* __restrict__ bih, const float* __restrict__ bhh,
    float* __restrict__ hout, int wf, int wid, int nw, int col, int kg)
{
    half8 wi[6], wh[6];
#pragma unroll
    for (int t = 0; t < 6; ++t) {
        wi[t] = *reinterpret_cast<const half8*>(Wihb + (size_t)(t * 16 + col) * 32 + kg * 8);
        wh[t] = *reinterpret_cast<const half8*>(Whhb + (size_t)(t * 16 + col) * 32 + kg * 8);
    }
    float br0  = bih[col]      + bhh[col];
    float bz0  = bih[32 + col] + bhh[32 + col];
    float bin0 = bih[64 + col];
    float bhn0 = bhh[64 + col];
    float br1  = bih[16 + col] + bhh[16 + col];
    float bz1  = bih[48 + col] + bhh[48 + col];
    float bin1 = bih[80 + col];
    float bhn1 = bhh[80 + col];

    for (int tile = wid; tile < ATILES; tile += nw) {
        int base = tile * 16;
        int a0   = base + col;
        int st = start[a0], en = st + cnt[a0];
        half8 hfrag = *reinterpret_cast<const half8*>(h + (size_t)a0 * 32 + kg * 8);

        float xs[8] = {0.f, 0.f, 0.f, 0.f, 0.f, 0.f, 0.f, 0.f};
        int p = st;
        while (p < en) {
            int n = en - p;
            half8 m0, m1, m2, m3;
            m0 = *reinterpret_cast<const half8*>(msgb + (size_t)p * 32 + kg * 8);
            if (n > 1) m1 = *reinterpret_cast<const half8*>(msgb + (size_t)(p + 1) * 32 + kg * 8);
            if (n > 2) m2 = *reinterpret_cast<const half8*>(msgb + (size_t)(p + 2) * 32 + kg * 8);
            if (n > 3) m3 = *reinterpret_cast<const half8*>(msgb + (size_t)(p + 3) * 32 + kg * 8);
#pragma unroll
            for (int j = 0; j < 8; ++j) xs[j] += (float)m0[j];
            if (n > 1) {
#pragma unroll
                for (int j = 0; j < 8; ++j) xs[j] += (float)m1[j];
            }
            if (n > 2) {
#pragma unroll
                for (int j = 0; j < 8; ++j) xs[j] += (float)m2[j];
            }
            if (n > 3) {
#pragma unroll
                for (int j = 0; j < 8; ++j) xs[j] += (float)m3[j];
            }
            p += 4;
        }
        half8 xfrag;
#pragma unroll
        for (int j = 0; j < 8; ++j) xfrag[j] = (f16)xs[j];

        f32x4 gi[6], gh[6];
#pragma unroll
        for (int t = 0; t < 6; ++t) {
            f32x4 z = {0.f, 0.f, 0.f, 0.f};
            gi[t] = __builtin_amdgcn_mfma_f32_16x16x32_f16(xfrag, wi[t], z, 0, 0, 0);
            gh[t] = __builtin_amdgcn_mfma_f32_16x16x32_f16(hfrag, wh[t], z, 0, 0, 0);
        }

#pragma unroll
        for (int hh = 0; hh < 2; ++hh) {
            float br  = hh ? br1  : br0;
            float bz  = hh ? bz1  : bz0;
            float bin = hh ? bin1 : bin0;
            float bhn = hh ? bhn1 : bhn0;
            int i = hh * 16 + col;
#pragma unroll
            for (int reg = 0; reg < 4; ++reg) {
                int a = base + kg * 4 + reg;
                float r = 1.f / (1.f + __expf(-(gi[hh][reg] + gh[hh][reg] + br)));
                float z = 1.f / (1.f + __expf(-(gi[2 + hh][reg] + gh[2 + hh][reg] + bz)));
                float n = tanhf(gi[4 + hh][reg] + bin + r * (gh[4 + hh][reg] + bhn));
                float hp = (float)h[(size_t)a * 32 + i];
                float o  = (1.f - z) * n + z * hp;
                if (wf) hout[(size_t)a * 32 + i] = o;
                h[(size_t)a * 32 + i] = (f16)o;
            }
        }
    }
}

// ---------------------------------------------------------------------------
// standalone kernels (fallback path — the proven r12 structure)
// ---------------------------------------------------------------------------
__global__ __launch_bounds__(256, 2) void msg_kernel(
    const f16* __restrict__ hb, const f16* __restrict__ bondp,
    const int* __restrict__ nbrp, const f16* __restrict__ Wbt,
    f16* __restrict__ msgb)
{
    int wave = threadIdx.x >> 6;
    int lane = threadIdx.x & 63;
    msg_body(hb, bondp, nbrp, Wbt, msgb,
             blockIdx.x * 4 + wave, gridDim.x << 2, lane & 15, lane >> 4);
}

__global__ __launch_bounds__(256) void gru_kernel(
    const f16* __restrict__ msgb, const int* __restrict__ start,
    const int* __restrict__ cnt, f16* __restrict__ hb,
    const f16* __restrict__ Wihb, const f16* __restrict__ Whhb,
    const float* __restrict__ bih, const float* __restrict__ bhh,
    float* __restrict__ hout, int wf)
{
    int wave = threadIdx.x >> 6;
    int lane = threadIdx.x & 63;
    gru_body(msgb, start, cnt, hb, Wihb, Whhb, bih, bhh, hout, wf,
             blockIdx.x * 4 + wave, gridDim.x << 2, lane & 15, lane >> 4);
}

// ---------------------------------------------------------------------------
// fused 4-step cooperative kernel (r14 structure, grid sized by occupancy)
// ---------------------------------------------------------------------------
__global__ __launch_bounds__(256, 2) void step_kernel(
    f16* __restrict__ h, const f16* __restrict__ bondp,
    const int* __restrict__ nbrp, const f16* __restrict__ Wbt,
    f16* __restrict__ msgb, const int* __restrict__ start,
    const int* __restrict__ cnt,
    const f16* __restrict__ Wihb, const f16* __restrict__ Whhb,
    const float* __restrict__ bih, const float* __restrict__ bhh,
    float* __restrict__ hout)
{
    cg::grid_group grid = cg::this_grid();
    int wave = threadIdx.x >> 6;
    int lane = threadIdx.x & 63;
    int col  = lane & 15;
    int kg   = lane >> 4;
    int wid  = blockIdx.x * 4 + wave;
    int nw   = gridDim.x << 2;

    for (int s = 0; s < STEPS; ++s) {
        msg_body(h, bondp, nbrp, Wbt, msgb, wid, nw, col, kg);
        grid.sync();
        gru_body(msgb, start, cnt, h, Wihb, Whhb, bih, bhh, hout,
                 (s == STEPS - 1) ? 1 : 0, wid, nw, col, kg);
        grid.sync();
    }
}

extern "C" void kernel_launch(void* const* d_in, const int* in_sizes, int n_in,
                              void* d_out, int out_size, void* d_ws, size_t ws_size,
                              hipStream_t stream)
{
    const float* atom = (const float*)d_in[0];
    const float* bond = (const float*)d_in[1];
    const int*   pair = (const int*)  d_in[2];
    const float* Wb   = (const float*)d_in[3];
    const float* bb   = (const float*)d_in[4];
    const float* W_ih = (const float*)d_in[5];
    const float* W_hh = (const float*)d_in[6];
    const float* b_ih = (const float*)d_in[7];
    const float* b_hh = (const float*)d_in[8];
    float* out = (float*)d_out;

    char* w = (char*)d_ws;
    f16* msg    = (f16*)w;                       // 19,200,000 B
    f16* hbf    = (f16*)(w + 19200000);          //  6,400,000
    f16* bondp  = (f16*)(w + 25600000);          //  9,600,000
    f16* Wbt    = (f16*)(w + 35200000);          //     34,816
    f16* Wihb   = Wbt + 17 * 32 * 32;            //      6,144
    f16* Whhb   = Wihb + 96 * 32;                //      6,144
    int* rowcnt = (int*)(w + 35248000);          //    400,000
    int* startp = (int*)(w + 35648000);          //    400,000
    int* nextp  = (int*)(w + 36048000);          //    400,000
    int* nbrp   = (int*)(w + 36448000);          //  1,200,000
    int* total  = (int*)(w + 37648000);          //          4

    // --- setup + CSR build (4 launches) ---
    const int setup_threads = NA * 32 / 8 + NA + 17 * 32 * 32 + 6144;
    setup_kernel<<<(setup_threads + 255) / 256, 256, 0, stream>>>(
        atom, Wb, bb, W_ih, W_hh, hbf, Wbt, Wihb, Whhb, rowcnt, total);
    hist_kernel<<<(NE + 255) / 256, 256, 0, stream>>>(pair, rowcnt);
    alloc_kernel<<<(NA + 1023) / 1024, 1024, 0, stream>>>(rowcnt, startp, nextp, total);
    scatter_kernel<<<(NE + 255) / 256, 256, 0, stream>>>(bond, pair, nextp, nbrp, bondp);

    // --- step loop: cooperative, grid sized to max co-residency ---
    int bpc = 0;
    hipError_t qe = hipOccupancyMaxActiveBlocksPerMultiprocessor(
        &bpc, (const void*)step_kernel, 256, 0);
    if (qe == hipSuccess && bpc >= 2) {
        int nblk = bpc * 256;                    // documented coop-safe maximum
        if (nblk > 2048) nblk = 2048;
        void* args[12];
        args[0]  = &hbf;   args[1]  = &bondp;  args[2]  = &nbrp;
        args[3]  = &Wbt;   args[4]  = &msg;    args[5]  = &startp;
        args[6]  = &rowcnt; args[7] = &Wihb;   args[8]  = &Whhb;
        args[9]  = (void*)&b_ih; args[10] = (void*)&b_hh; args[11] = &out;
        hipLaunchCooperativeKernel((void*)step_kernel, dim3(nblk), dim3(256),
                                   args, 0, stream);
    } else {
        const int gru_blocks = (ATILES + 3) / 4;
        for (int s = 0; s < STEPS; ++s) {
            msg_kernel<<<512, 256, 0, stream>>>(hbf, bondp, nbrp, Wbt, msg);
            gru_kernel<<<gru_blocks, 256, 0, stream>>>(msg, startp, rowcnt, hbf,
                                                       Wihb, Whhb, b_ih, b_hh, out,
                                                       (s == STEPS - 1) ? 1 : 0);
        }
    }
}

// Round 17
// 194.932 us; speedup vs baseline: 1.0493x; 1.0010x over previous
//
#include <hip/hip_runtime.h>
#include <hip/hip_cooperative_groups.h>

namespace cg = cooperative_groups;

#define NA 100000
#define NE 300000
#define STEPS 4
#define NTILES (NE / 16)        // 18750 (exact)
#define ATILES (NA / 16)        // 6250  (exact)

typedef _Float16 f16;
typedef _Float16 half8 __attribute__((ext_vector_type(8)));
using f32x4 = __attribute__((ext_vector_type(4))) float;

// ---------------------------------------------------------------------------
// shared phase bodies (identical arithmetic to proven r11/r12/r14 kernels)
// ---------------------------------------------------------------------------
__device__ __forceinline__ void msg_body(
    const f16* __restrict__ h, const f16* __restrict__ bondp,
    const int* __restrict__ nbrp, const f16* __restrict__ Wbt,
    f16* __restrict__ msgb, int wid, int nw, int col, int kg)
{
    half8 w0[17], w1[17];
#pragma unroll
    for (int t = 0; t < 17; ++t) {
        w0[t] = *reinterpret_cast<const half8*>(Wbt + (t * 32 + col) * 32 + kg * 8);
        w1[t] = *reinterpret_cast<const half8*>(Wbt + (t * 32 + 16 + col) * 32 + kg * 8);
    }
    int tile = wid;
    int pos = 0;
    half8 hf{}, cA{}, cB{};
    if (tile < NTILES) {
        pos = tile * 16 + col;
        int nbr0 = nbrp[pos];
        cA = *reinterpret_cast<const half8*>(bondp + (size_t)pos * 16);
        cB = *reinterpret_cast<const half8*>(bondp + (size_t)pos * 16 + 8);
        hf = *reinterpret_cast<const half8*>(h + (size_t)nbr0 * 32 + kg * 8);
    }
    while (tile < NTILES) {
        int tile2 = tile + nw;
        int pos2 = 0;
        half8 hf2{}, cA2{}, cB2{};
        if (tile2 < NTILES) {
            pos2 = tile2 * 16 + col;
            int nbr2 = nbrp[pos2];
            cA2 = *reinterpret_cast<const half8*>(bondp + (size_t)pos2 * 16);
            cB2 = *reinterpret_cast<const half8*>(bondp + (size_t)pos2 * 16 + 8);
            hf2 = *reinterpret_cast<const half8*>(h + (size_t)nbr2 * 32 + kg * 8);
        }
        f32x4 acc0 = {0.f, 0.f, 0.f, 0.f};
        f32x4 acc1 = {0.f, 0.f, 0.f, 0.f};
#pragma unroll
        for (int t = 0; t < 16; ++t) {
            f16 ch = (t < 8) ? cA[t] : cB[t - 8];
            half8 a = hf * ch;               // v_pk_mul_f16 x4
            acc0 = __builtin_amdgcn_mfma_f32_16x16x32_f16(w0[t], a, acc0, 0, 0, 0);
            acc1 = __builtin_amdgcn_mfma_f32_16x16x32_f16(w1[t], a, acc1, 0, 0, 0);
        }
        acc0 = __builtin_amdgcn_mfma_f32_16x16x32_f16(w0[16], hf, acc0, 0, 0, 0);
        acc1 = __builtin_amdgcn_mfma_f32_16x16x32_f16(w1[16], hf, acc1, 0, 0, 0);

        half8 so;   // i = kg*8 .. kg*8+7 (contiguous via Wbt row permute)
        so[0]=(f16)acc0[0]; so[1]=(f16)acc0[1]; so[2]=(f16)acc0[2]; so[3]=(f16)acc0[3];
        so[4]=(f16)acc1[0]; so[5]=(f16)acc1[1]; so[6]=(f16)acc1[2]; so[7]=(f16)acc1[3];
        *reinterpret_cast<half8*>(msgb + (size_t)pos * 32 + kg * 8) = so;

        tile = tile2; pos = pos2; hf = hf2; cA = cA2; cB = cB2;
    }
}

__device__ __forceinline__ void gru_body(
    const f16* __restrict__ msgb, const int* __restrict__ start,
    const int* __restrict__ cnt, f16* __restrict__ h,
    const f16* __restrict__ Wihb, const f16* __restrict__ Whhb,
    const float* __restrict__ bih, const float* __restrict__ bhh,
    float* __restrict__ hout, int wf, int wid, int nw, int col, int kg)
{
    half8 wi[6], wh[6];
#pragma unroll
    for (int t = 0; t < 6; ++t) {
        wi[t] = *reinterpret_cast<const half8*>(Wihb + (size_t)(t * 16 + col) * 32 + kg * 8);
        wh[t] = *reinterpret_cast<const half8*>(Whhb + (size_t)(t * 16 + col) * 32 + kg * 8);
    }
    float br0  = bih[col]      + bhh[col];
    float bz0  = bih[32 + col] + bhh[32 + col];
    float bin0 = bih[64 + col];
    float bhn0 = bhh[64 + col];
    float br1  = bih[16 + col] + bhh[16 + col];
    float bz1  = bih[48 + col] + bhh[48 + col];
    float bin1 = bih[80 + col];
    float bhn1 = bhh[80 + col];

    for (int tile = wid; tile < ATILES; tile += nw) {
        int base = tile * 16;
        int a0   = base + col;
        int st = start[a0], en = st + cnt[a0];
        half8 hfrag = *reinterpret_cast<const half8*>(h + (size_t)a0 * 32 + kg * 8);

        float xs[8] = {0.f, 0.f, 0.f, 0.f, 0.f, 0.f, 0.f, 0.f};
        int p = st;
        while (p < en) {
            int n = en - p;
            half8 m0, m1, m2, m3;
            m0 = *reinterpret_cast<const half8*>(msgb + (size_t)p * 32 + kg * 8);
            if (n > 1) m1 = *reinterpret_cast<const half8*>(msgb + (size_t)(p + 1) * 32 + kg * 8);
            if (n > 2) m2 = *reinterpret_cast<const half8*>(msgb + (size_t)(p + 2) * 32 + kg * 8);
            if (n > 3) m3 = *reinterpret_cast<const half8*>(msgb + (size_t)(p + 3) * 32 + kg * 8);
#pragma unroll
            for (int j = 0; j < 8; ++j) xs[j] += (float)m0[j];
            if (n > 1) {
#pragma unroll
                for (int j = 0; j < 8; ++j) xs[j] += (float)m1[j];
            }
            if (n > 2) {
#pragma unroll
                for (int j = 0; j < 8; ++j) xs[j] += (float)m2[j];
            }
            if (n > 3) {
#pragma unroll
                for (int j = 0; j < 8; ++j) xs[j] += (float)m3[j];
            }
            p += 4;
        }
        half8 xfrag;
#pragma unroll
        for (int j = 0; j < 8; ++j) xfrag[j] = (f16)xs[j];

        f32x4 gi[6], gh[6];
#pragma unroll
        for (int t = 0; t < 6; ++t) {
            f32x4 z = {0.f, 0.f, 0.f, 0.f};
            gi[t] = __builtin_amdgcn_mfma_f32_16x16x32_f16(xfrag, wi[t], z, 0, 0, 0);
            gh[t] = __builtin_amdgcn_mfma_f32_16x16x32_f16(hfrag, wh[t], z, 0, 0, 0);
        }

#pragma unroll
        for (int hh = 0; hh < 2; ++hh) {
            float br  = hh ? br1  : br0;
            float bz  = hh ? bz1  : bz0;
            float bin = hh ? bin1 : bin0;
            float bhn = hh ? bhn1 : bhn0;
            int i = hh * 16 + col;
#pragma unroll
            for (int reg = 0; reg < 4; ++reg) {
                int a = base + kg * 4 + reg;
                float r = 1.f / (1.f + __expf(-(gi[hh][reg] + gh[hh][reg] + br)));
                float z = 1.f / (1.f + __expf(-(gi[2 + hh][reg] + gh[2 + hh][reg] + bz)));
                float n = tanhf(gi[4 + hh][reg] + bin + r * (gh[4 + hh][reg] + bhn));
                float hp = (float)h[(size_t)a * 32 + i];
                float o  = (1.f - z) * n + z * hp;
                if (wf) hout[(size_t)a * 32 + i] = o;
                h[(size_t)a * 32 + i] = (f16)o;
            }
        }
    }
}

// ---------------------------------------------------------------------------
// setup body (shared by mega kernel phase 0 and the fallback setup_kernel)
// ---------------------------------------------------------------------------
__device__ __forceinline__ void setup_item(
    int t, const float* __restrict__ atom,
    const float* __restrict__ Wb, const float* __restrict__ bb,
    const float* __restrict__ Wih, const float* __restrict__ Whh,
    f16* __restrict__ hbf, f16* __restrict__ Wbt,
    f16* __restrict__ Wihb, f16* __restrict__ Whhb,
    int* __restrict__ rowcnt, int* __restrict__ total)
{
    const int NH8 = NA * 32 / 8;                 // 400000
    if (t < NH8) {
        float4 a = reinterpret_cast<const float4*>(atom)[2 * t];
        float4 b = reinterpret_cast<const float4*>(atom)[2 * t + 1];
        half8 o;
        o[0]=(f16)a.x; o[1]=(f16)a.y; o[2]=(f16)a.z; o[3]=(f16)a.w;
        o[4]=(f16)b.x; o[5]=(f16)b.y; o[6]=(f16)b.z; o[7]=(f16)b.w;
        reinterpret_cast<half8*>(hbf)[t] = o;
        return;
    }
    int u = t - NH8;
    if (u < NA) {
        rowcnt[u] = 0;
        if (u == 0) *total = 0;
        return;
    }
    int v = u - NA;
    if (v < 17 * 32 * 32) {
        int j = v & 31, i = (v >> 5) & 31, k = v >> 10;
        float val = (k < 16) ? Wb[k * 1024 + i * 32 + j] : bb[i * 32 + j];
        int row = ((i & 4) ? 16 : 0) + ((i >> 3) << 2) + (i & 3);  // i = kg*8.. permute
        Wbt[(k * 32 + row) * 32 + j] = (f16)val;
    } else if (v < 17 * 32 * 32 + 3072) {
        int q = v - 17 * 32 * 32;
        Wihb[q] = (f16)Wih[q];
    } else if (v < 17 * 32 * 32 + 6144) {
        int q = v - 17 * 32 * 32 - 3072;
        Whhb[q] = (f16)Whh[q];
    }
}

__device__ __forceinline__ void scatter_item(
    int e, const float* __restrict__ bond, const int* __restrict__ pair,
    int* __restrict__ next, int* __restrict__ nbrp, f16* __restrict__ bondp)
{
    int2 p = reinterpret_cast<const int2*>(pair)[e];
    int pos = atomicAdd(&next[p.x], 1);
    nbrp[pos] = p.y;
    const float4* b4 = reinterpret_cast<const float4*>(bond + (size_t)e * 16);
    float4 b0 = b4[0], b1 = b4[1], b2 = b4[2], b3 = b4[3];
    half8 o0, o1;
    o0[0]=(f16)b0.x; o0[1]=(f16)b0.y; o0[2]=(f16)b0.z; o0[3]=(f16)b0.w;
    o0[4]=(f16)b1.x; o0[5]=(f16)b1.y; o0[6]=(f16)b1.z; o0[7]=(f16)b1.w;
    o1[0]=(f16)b2.x; o1[1]=(f16)b2.y; o1[2]=(f16)b2.z; o1[3]=(f16)b2.w;
    o1[4]=(f16)b3.x; o1[5]=(f16)b3.y; o1[6]=(f16)b3.z; o1[7]=(f16)b3.w;
    half8* dst = reinterpret_cast<half8*>(bondp + (size_t)pos * 16);
    dst[0] = o0; dst[1] = o1;
}

#define SETUP_THREADS (NA * 32 / 8 + NA + 17 * 32 * 32 + 6144)

// ---------------------------------------------------------------------------
// THE single mega kernel: setup -> hist -> alloc -> scatter -> 4x(msg,gru)
// ---------------------------------------------------------------------------
__global__ __launch_bounds__(256, 2) void mega_kernel(
    const float* __restrict__ atom, const float* __restrict__ bond,
    const int* __restrict__ pair,
    const float* __restrict__ Wb, const float* __restrict__ bb,
    const float* __restrict__ Wih, const float* __restrict__ Whh,
    const float* __restrict__ bih, const float* __restrict__ bhh,
    f16* __restrict__ hbf, f16* __restrict__ Wbt,
    f16* __restrict__ Wihb, f16* __restrict__ Whhb,
    int* __restrict__ rowcnt, int* __restrict__ startp, int* __restrict__ nextp,
    int* __restrict__ nbrp, f16* __restrict__ bondp,
    f16* __restrict__ msgb, int* __restrict__ total,
    float* __restrict__ hout)
{
    __shared__ int scan[256];
    __shared__ int sbase;

    cg::grid_group grid = cg::this_grid();
    int gtid = blockIdx.x * 256 + threadIdx.x;
    int gsz  = gridDim.x * 256;

    // phase 0: converts + zeroing + weight prep
    for (int t = gtid; t < SETUP_THREADS; t += gsz)
        setup_item(t, atom, Wb, bb, Wih, Whh, hbf, Wbt, Wihb, Whhb, rowcnt, total);
    grid.sync();

    // phase 1: degree histogram
    for (int e = gtid; e < NE; e += gsz)
        atomicAdd(&rowcnt[reinterpret_cast<const int2*>(pair)[e].x], 1);
    grid.sync();

    // phase 2: segment allocation (256-chunk LDS scan + atomic base)
    const int NCHUNK = (NA + 255) / 256;
    for (int chunk = blockIdx.x; chunk < NCHUNK; chunk += gridDim.x) {
        int g = chunk * 256 + threadIdx.x;
        int v = (g < NA) ? rowcnt[g] : 0;
        scan[threadIdx.x] = v;
        __syncthreads();
        for (int off = 1; off < 256; off <<= 1) {
            int u = (threadIdx.x >= off) ? scan[threadIdx.x - off] : 0;
            __syncthreads();
            scan[threadIdx.x] += u;
            __syncthreads();
        }
        if (threadIdx.x == 255) sbase = atomicAdd(total, scan[255]);
        __syncthreads();
        if (g < NA) {
            int s = sbase + scan[threadIdx.x] - v;
            startp[g] = s;
            nextp[g]  = s;
        }
        __syncthreads();
    }
    grid.sync();

    // phase 3: scatter (nbr + bond fp16, dst-sorted)
    for (int e = gtid; e < NE; e += gsz)
        scatter_item(e, bond, pair, nextp, nbrp, bondp);
    grid.sync();

    // phase 4: the 4-step loop (proven r14 bodies)
    int wave = threadIdx.x >> 6;
    int lane = threadIdx.x & 63;
    int col  = lane & 15;
    int kg   = lane >> 4;
    int wid  = blockIdx.x * 4 + wave;
    int nw   = gridDim.x << 2;

    for (int s = 0; s < STEPS; ++s) {
        msg_body(hbf, bondp, nbrp, Wbt, msgb, wid, nw, col, kg);
        grid.sync();
        gru_body(msgb, startp, rowcnt, hbf, Wihb, Whhb, bih, bhh, hout,
                 (s == STEPS - 1) ? 1 : 0, wid, nw, col, kg);
        grid.sync();
    }
}

// ---------------------------------------------------------------------------
// fallback path kernels (proven r12/r16 structure)
// ---------------------------------------------------------------------------
__global__ __launch_bounds__(256) void setup_kernel(
    const float* __restrict__ atom,
    const float* __restrict__ Wb, const float* __restrict__ bb,
    const float* __restrict__ Wih, const float* __restrict__ Whh,
    f16* __restrict__ hbf, f16* __restrict__ Wbt,
    f16* __restrict__ Wihb, f16* __restrict__ Whhb,
    int* __restrict__ rowcnt, int* __restrict__ total)
{
    int t = blockIdx.x * 256 + threadIdx.x;
    if (t < SETUP_THREADS)
        setup_item(t, atom, Wb, bb, Wih, Whh, hbf, Wbt, Wihb, Whhb, rowcnt, total);
}

__global__ __launch_bounds__(256) void hist_kernel(
    const int* __restrict__ pair, int* __restrict__ cnt)
{
    int e = blockIdx.x * 256 + threadIdx.x;
    if (e < NE) atomicAdd(&cnt[reinterpret_cast<const int2*>(pair)[e].x], 1);
}

__global__ __launch_bounds__(1024) void alloc_kernel(
    const int* __restrict__ cnt, int* __restrict__ start,
    int* __restrict__ next, int* __restrict__ total)
{
    __shared__ int tmp[1024];
    __shared__ int base;
    int g = blockIdx.x * 1024 + threadIdx.x;
    int v = (g < NA) ? cnt[g] : 0;
    tmp[threadIdx.x] = v;
    __syncthreads();
    for (int off = 1; off < 1024; off <<= 1) {
        int u = (threadIdx.x >= off) ? tmp[threadIdx.x - off] : 0;
        __syncthreads();
        tmp[threadIdx.x] += u;
        __syncthreads();
    }
    if (threadIdx.x == 1023) base = atomicAdd(total, tmp[1023]);
    __syncthreads();
    if (g < NA) {
        int s = base + tmp[threadIdx.x] - v;
        start[g] = s;
        next[g] = s;
    }
}

__global__ __launch_bounds__(256) void scatter_kernel(
    const float* __restrict__ bond, const int* __restrict__ pair,
    int* __restrict__ next, int* __restrict__ nbrp, f16* __restrict__ bondp)
{
    int e = blockIdx.x * 256 + threadIdx.x;
    if (e < NE) scatter_item(e, bond, pair, next, nbrp, bondp);
}

__global__ __launch_bounds__(256, 2) void msg_kernel(
    const f16* __restrict__ hb, const f16* __restrict__ bondp,
    const int* __restrict__ nbrp, const f16* __restrict__ Wbt,
    f16* __restrict__ msgb)
{
    int wave = threadIdx.x >> 6;
    int lane = threadIdx.x & 63;
    msg_body(hb, bondp, nbrp, Wbt, msgb,
             blockIdx.x * 4 + wave, gridDim.x << 2, lane & 15, lane >> 4);
}

__global__ __launch_bounds__(256) void gru_kernel(
    const f16* __restrict__ msgb, const int* __restrict__ start,
    const int* __restrict__ cnt, f16* __restrict__ hb,
    const f16* __restrict__ Wihb, const f16* __restrict__ Whhb,
    const float* __restrict__ bih, const float* __restrict__ bhh,
    float* __restrict__ hout, int wf)
{
    int wave = threadIdx.x >> 6;
    int lane = threadIdx.x & 63;
    gru_body(msgb, start, cnt, hb, Wihb, Whhb, bih, bhh, hout, wf,
             blockIdx.x * 4 + wave, gridDim.x << 2, lane & 15, lane >> 4);
}

extern "C" void kernel_launch(void* const* d_in, const int* in_sizes, int n_in,
                              void* d_out, int out_size, void* d_ws, size_t ws_size,
                              hipStream_t stream)
{
    const float* atom = (const float*)d_in[0];
    const float* bond = (const float*)d_in[1];
    const int*   pair = (const int*)  d_in[2];
    const float* Wb   = (const float*)d_in[3];
    const float* bb   = (const float*)d_in[4];
    const float* W_ih = (const float*)d_in[5];
    const float* W_hh = (const float*)d_in[6];
    const float* b_ih = (const float*)d_in[7];
    const float* b_hh = (const float*)d_in[8];
    float* out = (float*)d_out;

    char* w = (char*)d_ws;
    f16* msg    = (f16*)w;                       // 19,200,000 B
    f16* hbf    = (f16*)(w + 19200000);          //  6,400,000
    f16* bondp  = (f16*)(w + 25600000);          //  9,600,000
    f16* Wbt    = (f16*)(w + 35200000);          //     34,816
    f16* Wihb   = Wbt + 17 * 32 * 32;            //      6,144
    f16* Whhb   = Wihb + 96 * 32;                //      6,144
    int* rowcnt = (int*)(w + 35248000);          //    400,000
    int* startp = (int*)(w + 35648000);          //    400,000
    int* nextp  = (int*)(w + 36048000);          //    400,000
    int* nbrp   = (int*)(w + 36448000);          //  1,200,000
    int* total  = (int*)(w + 37648000);          //          4

    int bpc = 0;
    hipError_t qe = hipOccupancyMaxActiveBlocksPerMultiprocessor(
        &bpc, (const void*)mega_kernel, 256, 0);
    if (qe == hipSuccess && bpc >= 2) {
        int nblk = bpc * 256;
        if (nblk > 2048) nblk = 2048;
        void* args[21];
        args[0]  = (void*)&atom;  args[1]  = (void*)&bond;  args[2]  = (void*)&pair;
        args[3]  = (void*)&Wb;    args[4]  = (void*)&bb;
        args[5]  = (void*)&W_ih;  args[6]  = (void*)&W_hh;
        args[7]  = (void*)&b_ih;  args[8]  = (void*)&b_hh;
        args[9]  = &hbf;   args[10] = &Wbt;   args[11] = &Wihb;  args[12] = &Whhb;
        args[13] = &rowcnt; args[14] = &startp; args[15] = &nextp;
        args[16] = &nbrp;  args[17] = &bondp; args[18] = &msg;
        args[19] = &total; args[20] = &out;
        hipLaunchCooperativeKernel((void*)mega_kernel, dim3(nblk), dim3(256),
                                   args, 0, stream);
    } else {
        // proven multi-kernel fallback
        setup_kernel<<<(SETUP_THREADS + 255) / 256, 256, 0, stream>>>(
            atom, Wb, bb, W_ih, W_hh, hbf, Wbt, Wihb, Whhb, rowcnt, total);
        hist_kernel<<<(NE + 255) / 256, 256, 0, stream>>>(pair, rowcnt);
        alloc_kernel<<<(NA + 1023) / 1024, 1024, 0, stream>>>(rowcnt, startp, nextp, total);
        scatter_kernel<<<(NE + 255) / 256, 256, 0, stream>>>(bond, pair, nextp, nbrp, bondp);
        const int gru_blocks = (ATILES + 3) / 4;
        for (int s = 0; s < STEPS; ++s) {
            msg_kernel<<<512, 256, 0, stream>>>(hbf, bondp, nbrp, Wbt, msg);
            gru_kernel<<<gru_blocks, 256, 0, stream>>>(msg, startp, rowcnt, hbf,
                                                       Wihb, Whhb, b_ih, b_hh, out,
                                                       (s == STEPS - 1) ? 1 : 0);
        }
    }
}